// Round 1
// baseline (445.554 us; speedup 1.0000x reference)
//
#include <hip/hip_runtime.h>
#include <hip/hip_bf16.h>
#include <stdint.h>

// MultiHeadAttention: x[4,2048,1024] fp32, mask[4,2048] i32,
// w_qkv[3072,1024], w_tail[1024,1024], b_tail[1024] -> out[4,2048,1024] fp32
// Pipeline: cvt->bf16, GEMM1 (qkv proj, scatter to [bh][3][t][64]),
// flash attention, GEMM2 (+bias, fp32 out).

typedef __attribute__((ext_vector_type(8))) short short8;
typedef __attribute__((ext_vector_type(4))) float f32x4;

#define T_SEQ 2048
#define NHEAD 16
#define DHEAD 64
#define DMODEL 1024

__device__ __forceinline__ ushort f2bf(float f) {
  uint32_t u = __float_as_uint(f);
  uint32_t r = (u + 0x7FFFu + ((u >> 16) & 1u)) >> 16;
  return (ushort)r;
}
__device__ __forceinline__ float bf2f(ushort b) {
  return __uint_as_float(((uint32_t)b) << 16);
}

__device__ __forceinline__ void gload_lds16(const ushort* g, ushort* l) {
  __builtin_amdgcn_global_load_lds(
      (const __attribute__((address_space(1))) void*)g,
      (__attribute__((address_space(3))) void*)l, 16, 0, 0);
}

// ---------------- fp32 -> bf16 conversion ----------------
__global__ void cvt_f32_bf16(const float* __restrict__ in,
                             ushort* __restrict__ out, int n8) {
  int i = blockIdx.x * blockDim.x + threadIdx.x;
  if (i < n8) {
    const float4* p = (const float4*)(in + (size_t)i * 8);
    float4 a = p[0], b = p[1];
    short8 o;
    o[0] = (short)f2bf(a.x); o[1] = (short)f2bf(a.y);
    o[2] = (short)f2bf(a.z); o[3] = (short)f2bf(a.w);
    o[4] = (short)f2bf(b.x); o[5] = (short)f2bf(b.y);
    o[6] = (short)f2bf(b.z); o[7] = (short)f2bf(b.w);
    *(short8*)(out + (size_t)i * 8) = o;
  }
}

// ---------------- bf16 GEMM: C = A * B^T ----------------
// A [M][K] bf16 row-major, B [N][K] bf16 row-major (both K-contiguous).
// 128x128 tile, BK=64, 4 waves (2x2), each wave 64x64 via 4x4 16x16x32 MFMA.
// EPI==0: scatter-store bf16 qkv into [ (b*16+h)*3+sel ][t][d]
// EPI==1: fp32 store to Cout[M][N] + bias
template <int EPI>
__launch_bounds__(256)
__global__ void gemm_bt(const ushort* __restrict__ A,
                        const ushort* __restrict__ B,
                        void* __restrict__ Cout,
                        const float* __restrict__ bias,
                        int M, int N, int K) {
  __shared__ ushort sA[128 * 64];
  __shared__ ushort sB[128 * 64];
  const int tid = threadIdx.x;
  const int lane = tid & 63;
  const int wid = tid >> 6;
  const int wr = wid >> 1, wc = wid & 1;
  const int bm = blockIdx.x * 128;
  const int bn = blockIdx.y * 128;
  const int l15 = lane & 15;
  const int lg = lane >> 4;

  f32x4 acc[4][4] = {};

  for (int k0 = 0; k0 < K; k0 += 64) {
#pragma unroll
    for (int r = 0; r < 4; ++r) {
      int c = r * 256 + tid;
      int row = c >> 3, ci = c & 7;
      gload_lds16(A + (size_t)(bm + row) * K + k0 + ci * 8, sA + c * 8);
      gload_lds16(B + (size_t)(bn + row) * K + k0 + ci * 8, sB + c * 8);
    }
    __syncthreads();
#pragma unroll
    for (int ks = 0; ks < 2; ++ks) {
      short8 af[4], bfr[4];
#pragma unroll
      for (int m = 0; m < 4; ++m)
        af[m] = *(const short8*)&sA[(wr * 64 + m * 16 + l15) * 64 + ks * 32 + lg * 8];
#pragma unroll
      for (int n = 0; n < 4; ++n)
        bfr[n] = *(const short8*)&sB[(wc * 64 + n * 16 + l15) * 64 + ks * 32 + lg * 8];
#pragma unroll
      for (int m = 0; m < 4; ++m)
#pragma unroll
        for (int n = 0; n < 4; ++n)
          acc[m][n] = __builtin_amdgcn_mfma_f32_16x16x32_bf16(af[m], bfr[n], acc[m][n], 0, 0, 0);
    }
    __syncthreads();
  }

  if (EPI == 0) {
    ushort* qkvb = (ushort*)Cout;
#pragma unroll
    for (int m = 0; m < 4; ++m)
#pragma unroll
      for (int n = 0; n < 4; ++n)
#pragma unroll
        for (int r = 0; r < 4; ++r) {
          int gr = bm + wr * 64 + m * 16 + lg * 4 + r;  // = b*T + t
          int gc = bn + wc * 64 + n * 16 + l15;         // o in [0,3072)
          int b = gr >> 11, t = gr & (T_SEQ - 1);
          int h = gc / 192, rem = gc - h * 192;
          int sel = rem >> 6, d = rem & 63;
          size_t dst = ((size_t)((b * NHEAD + h) * 3 + sel) * T_SEQ + t) * DHEAD + d;
          qkvb[dst] = f2bf(acc[m][n][r]);
        }
  } else {
    float* out = (float*)Cout;
#pragma unroll
    for (int m = 0; m < 4; ++m)
#pragma unroll
      for (int n = 0; n < 4; ++n) {
        int gc = bn + wc * 64 + n * 16 + l15;
        float bv = bias[gc];
#pragma unroll
        for (int r = 0; r < 4; ++r) {
          int gr = bm + wr * 64 + m * 16 + lg * 4 + r;
          out[(size_t)gr * N + gc] = acc[m][n][r] + bv;
        }
      }
  }
}

// ---------------- flash attention ----------------
// qkv layout: [(b*16+h)*3 + sel][2048][64] bf16.  Q pre-scaled by 1/8 at load.
// Block: 256 threads (4 waves), each wave 32 q rows -> QBLK=128. KBLK=64.
// Output attn bf16 [b*2048+t][h*64+d].
__launch_bounds__(256)
__global__ void attn_fwd(const ushort* __restrict__ qkv,
                         const int* __restrict__ mask,
                         ushort* __restrict__ attn) {
  __shared__ ushort sK[64 * 64];
  __shared__ ushort sVT[64 * 64];
  __shared__ ushort sP[4][32 * 64];

  const int tid = threadIdx.x;
  const int lane = tid & 63;
  const int wid = tid >> 6;
  const int l15 = lane & 15;
  const int lg = lane >> 4;
  const int qt = blockIdx.x;   // 0..15
  const int bh = blockIdx.y;   // 0..63
  const int b = bh >> 4, h = bh & 15;

  const ushort* Qp = qkv + (size_t)(bh * 3 + 0) * T_SEQ * DHEAD;
  const ushort* Kp = qkv + (size_t)(bh * 3 + 1) * T_SEQ * DHEAD;
  const ushort* Vp = qkv + (size_t)(bh * 3 + 2) * T_SEQ * DHEAD;
  const int* mrow = mask + b * T_SEQ;

  const int qbase = qt * 128 + wid * 32;

  // Q fragments, pre-scaled by 0.125 (exact exponent shift in bf16)
  short8 qf[2][2];
#pragma unroll
  for (int m = 0; m < 2; ++m)
#pragma unroll
    for (int ks = 0; ks < 2; ++ks) {
      short8 raw = *(const short8*)&Qp[(size_t)(qbase + m * 16 + l15) * 64 + ks * 32 + lg * 8];
#pragma unroll
      for (int e = 0; e < 8; ++e)
        qf[m][ks][e] = (short)f2bf(bf2f((ushort)raw[e]) * 0.125f);
    }

  float mrun[2][4], lrun[2][4];
#pragma unroll
  for (int m = 0; m < 2; ++m)
#pragma unroll
    for (int r = 0; r < 4; ++r) { mrun[m][r] = -1e30f; lrun[m][r] = 0.f; }
  f32x4 oacc[2][4] = {};

  for (int kt = 0; kt < T_SEQ / 64; ++kt) {
    const int kb = kt * 64;
    // stage K tile [64][64] linear via global_load_lds (2 rounds)
#pragma unroll
    for (int r = 0; r < 2; ++r) {
      int c = r * 256 + tid;
      int row = c >> 3, ci = c & 7;
      gload_lds16(Kp + (size_t)(kb + row) * 64 + ci * 8, sK + c * 8);
    }
    // stage V transposed: sVT[d][kk]
#pragma unroll
    for (int r = 0; r < 2; ++r) {
      int c = r * 256 + tid;
      int kk = c >> 3, d0 = (c & 7) * 8;
      short8 v = *(const short8*)&Vp[(size_t)(kb + kk) * 64 + d0];
#pragma unroll
      for (int j = 0; j < 8; ++j) sVT[(d0 + j) * 64 + kk] = (ushort)v[j];
    }
    __syncthreads();

    // S = (Q/8) K^T  (per wave: 32x64)
    f32x4 sacc[2][4] = {};
#pragma unroll
    for (int ks = 0; ks < 2; ++ks) {
      short8 kf[4];
#pragma unroll
      for (int n = 0; n < 4; ++n)
        kf[n] = *(const short8*)&sK[(n * 16 + l15) * 64 + ks * 32 + lg * 8];
#pragma unroll
      for (int m = 0; m < 2; ++m)
#pragma unroll
        for (int n = 0; n < 4; ++n)
          sacc[m][n] = __builtin_amdgcn_mfma_f32_16x16x32_bf16(qf[m][ks], kf[n], sacc[m][n], 0, 0, 0);
    }

    // mask (key mask, same for every query row)
    int keep[4];
#pragma unroll
    for (int n = 0; n < 4; ++n) keep[n] = mrow[kb + n * 16 + l15];
#pragma unroll
    for (int m = 0; m < 2; ++m)
#pragma unroll
      for (int n = 0; n < 4; ++n)
        if (!keep[n])
#pragma unroll
          for (int r = 0; r < 4; ++r) sacc[m][n][r] = -1e30f;

    // online softmax per (m, reg) row; row spread over 16-lane group
#pragma unroll
    for (int m = 0; m < 2; ++m) {
      float tmax[4];
#pragma unroll
      for (int r = 0; r < 4; ++r) {
        float v = sacc[m][0][r];
#pragma unroll
        for (int n = 1; n < 4; ++n) v = fmaxf(v, sacc[m][n][r]);
        tmax[r] = v;
      }
#pragma unroll
      for (int off = 1; off < 16; off <<= 1)
#pragma unroll
        for (int r = 0; r < 4; ++r) tmax[r] = fmaxf(tmax[r], __shfl_xor(tmax[r], off));

      float alpha[4], rsum[4];
#pragma unroll
      for (int r = 0; r < 4; ++r) {
        float mn = fmaxf(mrun[m][r], tmax[r]);
        alpha[r] = __expf(mrun[m][r] - mn);
        mrun[m][r] = mn;
        rsum[r] = 0.f;
      }
#pragma unroll
      for (int n = 0; n < 4; ++n)
#pragma unroll
        for (int r = 0; r < 4; ++r) {
          float p = __expf(sacc[m][n][r] - mrun[m][r]);
          sacc[m][n][r] = p;
          rsum[r] += p;
        }
#pragma unroll
      for (int off = 1; off < 16; off <<= 1)
#pragma unroll
        for (int r = 0; r < 4; ++r) rsum[r] += __shfl_xor(rsum[r], off);
#pragma unroll
      for (int r = 0; r < 4; ++r) lrun[m][r] = lrun[m][r] * alpha[r] + rsum[r];
#pragma unroll
      for (int dt = 0; dt < 4; ++dt)
#pragma unroll
        for (int r = 0; r < 4; ++r) oacc[m][dt][r] *= alpha[r];
      // P -> per-wave LDS (C-layout -> A-layout refragmentation)
#pragma unroll
      for (int n = 0; n < 4; ++n)
#pragma unroll
        for (int r = 0; r < 4; ++r)
          sP[wid][(m * 16 + lg * 4 + r) * 64 + n * 16 + l15] = f2bf(sacc[m][n][r]);
    }

    // O += P V   (A = P from sP, B = V^T rows = d)
#pragma unroll
    for (int ks = 0; ks < 2; ++ks) {
      short8 pf[2];
#pragma unroll
      for (int m = 0; m < 2; ++m)
        pf[m] = *(const short8*)&sP[wid][(m * 16 + l15) * 64 + ks * 32 + lg * 8];
#pragma unroll
      for (int dt = 0; dt < 4; ++dt) {
        short8 vf = *(const short8*)&sVT[(dt * 16 + l15) * 64 + ks * 32 + lg * 8];
#pragma unroll
        for (int m = 0; m < 2; ++m)
          oacc[m][dt] = __builtin_amdgcn_mfma_f32_16x16x32_bf16(pf[m], vf, oacc[m][dt], 0, 0, 0);
      }
    }
    __syncthreads();
  }

  // epilogue: attn[b*T+t][h*64+d] = O / l
#pragma unroll
  for (int m = 0; m < 2; ++m)
#pragma unroll
    for (int dt = 0; dt < 4; ++dt)
#pragma unroll
      for (int r = 0; r < 4; ++r) {
        int t = qbase + m * 16 + lg * 4 + r;
        int d = dt * 16 + l15;
        float o = oacc[m][dt][r] / lrun[m][r];
        attn[(size_t)(b * T_SEQ + t) * DMODEL + h * DHEAD + d] = f2bf(o);
      }
}

// ---------------- launch ----------------
extern "C" void kernel_launch(void* const* d_in, const int* in_sizes, int n_in,
                              void* d_out, int out_size, void* d_ws, size_t ws_size,
                              hipStream_t stream) {
  (void)in_sizes; (void)n_in; (void)out_size; (void)ws_size;
  const float* x      = (const float*)d_in[0];  // [4,2048,1024]
  const int*   mask   = (const int*)d_in[1];    // [4,2048]
  const float* w_qkv  = (const float*)d_in[2];  // [3072,1024]
  const float* w_tail = (const float*)d_in[3];  // [1024,1024]
  const float* b_tail = (const float*)d_in[4];  // [1024]
  float* out = (float*)d_out;

  const size_t M = 4 * 2048;
  ushort* xb     = (ushort*)d_ws;                    // 8192*1024
  ushort* wqkvb  = xb + M * DMODEL;                  // 3072*1024
  ushort* wtailb = wqkvb + 3 * DMODEL * DMODEL;      // 1024*1024
  ushort* qkvb   = wtailb + DMODEL * DMODEL;         // 64*3*2048*64
  ushort* attnb  = qkvb + (size_t)64 * 3 * T_SEQ * DHEAD;  // 8192*1024

  {
    int n8 = (int)(M * DMODEL / 8);
    cvt_f32_bf16<<<n8 / 256, 256, 0, stream>>>(x, xb, n8);
  }
  {
    int n8 = 3 * DMODEL * DMODEL / 8;
    cvt_f32_bf16<<<n8 / 256, 256, 0, stream>>>(w_qkv, wqkvb, n8);
  }
  {
    int n8 = DMODEL * DMODEL / 8;
    cvt_f32_bf16<<<n8 / 256, 256, 0, stream>>>(w_tail, wtailb, n8);
  }

  // GEMM1: qkv = x @ w_qkv^T ; scatter to [bh][3][t][64]
  gemm_bt<0><<<dim3(M / 128, 3 * DMODEL / 128), 256, 0, stream>>>(
      xb, wqkvb, qkvb, nullptr, (int)M, 3 * DMODEL, DMODEL);

  // attention
  attn_fwd<<<dim3(T_SEQ / 128, 64), 256, 0, stream>>>(qkvb, mask, attnb);

  // GEMM2: out = attn @ w_tail^T + b_tail (fp32 out)
  gemm_bt<1><<<dim3(M / 128, DMODEL / 128), 256, 0, stream>>>(
      attnb, wtailb, out, b_tail, (int)M, DMODEL, DMODEL);
}